// Round 1
// baseline (443.666 us; speedup 1.0000x reference)
//
#include <hip/hip_runtime.h>
#include <math.h>

#define BB 64
#define SS 256

static __device__ __forceinline__ float relu_(float v){ return v > 0.f ? v : 0.f; }

// ---------------- conv1 (3->16, VALID, k3) + avgpool2 + relu ----------------
__global__ void k_conv1(const float* __restrict__ x, const float* __restrict__ w,
                        const float* __restrict__ bias, float* __restrict__ h1) {
    int idx = blockIdx.x * 256 + threadIdx.x;
    const int N = BB * 16 * 31 * 31;
    if (idx >= N) return;
    int xo = idx % 31; int t = idx / 31; int yo = t % 31; t /= 31; int o = t % 16; int b = t / 16;
    const float* xb = x + (size_t)b * 3 * 4096;
    const float* wo = w + o * 27;
    float acc = 4.0f * bias[o];
    #pragma unroll
    for (int dy = 0; dy < 2; ++dy)
    #pragma unroll
    for (int dx = 0; dx < 2; ++dx) {
        int cy = 2 * yo + dy, cx = 2 * xo + dx;
        #pragma unroll
        for (int ci = 0; ci < 3; ++ci)
        #pragma unroll
        for (int ky = 0; ky < 3; ++ky)
        #pragma unroll
        for (int kx = 0; kx < 3; ++kx)
            acc += (xb[ci * 4096 + (cy + ky) * 64 + (cx + kx)] - 0.5f) * wo[ci * 9 + ky * 3 + kx];
    }
    h1[idx] = relu_(acc * 0.25f);
}

// ---------------- conv2 (16->32, pad1, k3) + avgpool2 + relu ----------------
__global__ void k_conv2(const float* __restrict__ h1, const float* __restrict__ w,
                        const float* __restrict__ bias, float* __restrict__ h2) {
    int idx = blockIdx.x * 256 + threadIdx.x;
    const int N = BB * 32 * 15 * 15;
    if (idx >= N) return;
    int xo = idx % 15; int t = idx / 15; int yo = t % 15; t /= 15; int o = t % 32; int b = t / 32;
    const float* hb = h1 + (size_t)b * 16 * 961;
    const float* wo = w + o * 144;
    float acc = 4.0f * bias[o];
    for (int dy = 0; dy < 2; ++dy)
    for (int dx = 0; dx < 2; ++dx) {
        int Y = 2 * yo + dy, X = 2 * xo + dx;
        for (int ci = 0; ci < 16; ++ci) {
            const float* hc = hb + ci * 961;
            const float* wc = wo + ci * 9;
            #pragma unroll
            for (int ky = 0; ky < 3; ++ky) {
                int iy = Y - 1 + ky; if (iy < 0 || iy > 30) continue;
                #pragma unroll
                for (int kx = 0; kx < 3; ++kx) {
                    int ix = X - 1 + kx; if (ix < 0 || ix > 30) continue;
                    acc += hc[iy * 31 + ix] * wc[ky * 3 + kx];
                }
            }
        }
    }
    h2[idx] = relu_(acc * 0.25f);
}

// ---------------- conv3 (32->32, pad1, k3) + relu ----------------
__global__ void k_conv3(const float* __restrict__ h2, const float* __restrict__ w,
                        const float* __restrict__ bias, float* __restrict__ h3) {
    int idx = blockIdx.x * 256 + threadIdx.x;
    const int N = BB * 32 * 15 * 15;
    if (idx >= N) return;
    int xo = idx % 15; int t = idx / 15; int yo = t % 15; t /= 15; int o = t % 32; int b = t / 32;
    const float* hb = h2 + (size_t)b * 32 * 225;
    const float* wo = w + o * 288;
    float acc = bias[o];
    for (int ci = 0; ci < 32; ++ci) {
        const float* hc = hb + ci * 225;
        const float* wc = wo + ci * 9;
        #pragma unroll
        for (int ky = 0; ky < 3; ++ky) {
            int iy = yo - 1 + ky; if (iy < 0 || iy > 14) continue;
            #pragma unroll
            for (int kx = 0; kx < 3; ++kx) {
                int ix = xo - 1 + kx; if (ix < 0 || ix > 14) continue;
                acc += hc[iy * 15 + ix] * wc[ky * 3 + kx];
            }
        }
    }
    h3[idx] = relu_(acc);
}

// ---------------- vision encoder linear 7200 -> 8 ----------------
__global__ void k_venc(const float* __restrict__ h3, const float* __restrict__ w,
                       const float* __restrict__ bias, float* __restrict__ ve) {
    int b = blockIdx.x >> 3; int f = blockIdx.x & 7; int tid = threadIdx.x;
    const float* hb = h3 + (size_t)b * 7200;
    const float* wf = w + (size_t)f * 7200;
    float s = 0.f;
    for (int i = tid; i < 7200; i += 256) s += hb[i] * wf[i];
    __shared__ float r[256];
    r[tid] = s; __syncthreads();
    for (int st = 128; st > 0; st >>= 1) { if (tid < st) r[tid] += r[tid + st]; __syncthreads(); }
    if (tid == 0) ve[b * 8 + f] = r[0] + bias[f];
}

// ---------------- target encoder: x[:, :, 0, 0] -> 64 -> 14 ----------------
__global__ void k_tenc(const float* __restrict__ x,
                       const float* __restrict__ w1, const float* __restrict__ b1,
                       const float* __restrict__ w2, const float* __restrict__ b2,
                       float* __restrict__ te) {
    int b = blockIdx.x; int tid = threadIdx.x; // 64 threads
    __shared__ float tc[3]; __shared__ float tt[64];
    if (tid < 3) tc[tid] = x[(size_t)b * 12288 + tid * 4096];
    __syncthreads();
    float v = b1[tid] + tc[0] * w1[tid * 3] + tc[1] * w1[tid * 3 + 1] + tc[2] * w1[tid * 3 + 2];
    tt[tid] = relu_(v);
    __syncthreads();
    if (tid < 14) {
        float e = b2[tid];
        for (int o = 0; o < 64; ++o) e += tt[o] * w2[tid * 64 + o];
        te[b * 14 + tid] = e;
    }
}

// ---------------- fused: cost = edges.min(-1), min_out = edges.min(axis=2) ----------------
__global__ void k_cost(const float* __restrict__ edges, float* __restrict__ cost,
                       float* __restrict__ minout) {
    int bi = blockIdx.x;            // b*256 + i
    int j = threadIdx.x;            // 0..255
    const float* e = edges + ((size_t)bi * 256 + j) * 6;
    float m0 = e[0], m1 = e[1], m2 = e[2], m3 = e[3], m4 = e[4], m5 = e[5];
    float c = fminf(fminf(fminf(m0, m1), fminf(m2, m3)), fminf(m4, m5));
    cost[(size_t)bi * 256 + j] = c;
    __shared__ float red[6][256];
    red[0][j] = m0; red[1][j] = m1; red[2][j] = m2; red[3][j] = m3; red[4][j] = m4; red[5][j] = m5;
    __syncthreads();
    for (int st = 128; st > 0; st >>= 1) {
        if (j < st) {
            #pragma unroll
            for (int q = 0; q < 6; ++q) red[q][j] = fminf(red[q][j], red[q][j + st]);
        }
        __syncthreads();
    }
    if (j < 6) minout[(size_t)bi * 6 + j] = red[j][0];
}

// ---------------- dists + argmin -> closest ----------------
__global__ void k_closest(const float* __restrict__ ve, const float* __restrict__ nodes,
                          int* __restrict__ closest) {
    int b = blockIdx.x, s = threadIdx.x;
    const float* n = nodes + ((size_t)b * 256 + s) * 8;
    const float* v = ve + b * 8;
    float acc = 0.f;
    #pragma unroll
    for (int f = 0; f < 8; ++f) { float d = v[f] - n[f]; acc += d * d; }
    __shared__ float val[256]; __shared__ int idx[256];
    val[s] = acc; idx[s] = s; __syncthreads();
    for (int st = 128; st > 0; st >>= 1) {
        if (s < st) {
            float ov = val[s + st]; int oi = idx[s + st];
            if (ov < val[s] || (ov == val[s] && oi < idx[s])) { val[s] = ov; idx[s] = oi; }
        }
        __syncthreads();
    }
    if (s == 0) closest[b] = idx[0];
}

// ---------------- Bellman relaxation scan (fixed-point early exit == bitwise identical) ----------------
__global__ void k_bellman(const float* __restrict__ cost, const int* __restrict__ closest,
                          float* __restrict__ dout) {
    int b = blockIdx.x; int t = threadIdx.x;
    const float* cb = cost + (size_t)b * 65536;
    __shared__ float d[256]; __shared__ int changed;
    int src = closest[b];
    float dv = cb[src * 256 + t];
    if (t == src) dv = 0.f;
    d[t] = dv;
    __syncthreads();
    for (int it = 0; it < 255; ++it) {
        float m = 3.402823466e+38f;
        for (int j = 0; j < 256; j += 4) {
            float a0 = d[j]     + cb[(j    ) * 256 + t];
            float a1 = d[j + 1] + cb[(j + 1) * 256 + t];
            float a2 = d[j + 2] + cb[(j + 2) * 256 + t];
            float a3 = d[j + 3] + cb[(j + 3) * 256 + t];
            m = fminf(m, fminf(fminf(a0, a1), fminf(a2, a3)));
        }
        float nd = fminf(dv, m);
        int ch = nd < dv;
        dv = nd;
        __syncthreads();              // all reads of d done
        if (t == 0) changed = 0;
        __syncthreads();
        d[t] = dv;
        if (ch) changed = 1;
        __syncthreads();              // d + changed visible
        if (!changed) break;          // fixed point: further iters identity
    }
    dout[(size_t)b * 256 + t] = dv;
}

// ---------------- top-K(4) smallest + build seq (B,5,14) ----------------
__global__ void k_seq(const float* __restrict__ dvec, const float* __restrict__ tenc,
                      const float* __restrict__ nodes, const float* __restrict__ minout,
                      float* __restrict__ seq, int* __restrict__ topk) {
    int b = blockIdx.x, t = threadIdx.x;
    float dv = dvec[(size_t)b * 256 + t];
    if (isinf(dv)) dv = 1e9f;
    float myv = dv;
    __shared__ float val[256]; __shared__ int idx[256]; __shared__ int sel[4];
    for (int k = 0; k < 4; ++k) {
        val[t] = myv; idx[t] = t; __syncthreads();
        for (int st = 128; st > 0; st >>= 1) {
            if (t < st) {
                float ov = val[t + st]; int oi = idx[t + st];
                if (ov < val[t] || (ov == val[t] && oi < idx[t])) { val[t] = ov; idx[t] = oi; }
            }
            __syncthreads();
        }
        if (t == 0) sel[k] = idx[0];
        __syncthreads();
        if (t == sel[k]) myv = 3.402823466e+38f;
    }
    if (t < 14) seq[(size_t)b * 70 + t] = tenc[b * 14 + t];
    if (t >= 64 && t < 64 + 56) {
        int u = t - 64; int k = u / 14; int c = u % 14; int id_ = sel[k];
        float v = (c < 8) ? nodes[((size_t)b * 256 + id_) * 8 + c]
                          : minout[((size_t)b * 256 + id_) * 6 + (c - 8)];
        seq[(size_t)b * 70 + (1 + k) * 14 + c] = v;
    }
    if (t < 4) topk[b * 4 + t] = sel[t];
}

// ---------------- transformer block + MLP heads, one block per batch ----------------
__global__ void k_head(const float* __restrict__ seq,
                       const float* __restrict__ Wi, const float* __restrict__ bi_,
                       const float* __restrict__ Wo, const float* __restrict__ bo,
                       const float* __restrict__ g1, const float* __restrict__ be1,
                       const float* __restrict__ g2, const float* __restrict__ be2,
                       const float* __restrict__ W1, const float* __restrict__ bf1,
                       const float* __restrict__ W2, const float* __restrict__ bf2,
                       const float* __restrict__ H1, const float* __restrict__ hb1,
                       const float* __restrict__ H2, const float* __restrict__ hb2,
                       const float* __restrict__ H3, const float* __restrict__ hb3,
                       float* __restrict__ out) {
    int b = blockIdx.x, t = threadIdx.x;
    __shared__ float sq[70], qkv[210], sc[25], tmp[70], f1[140], h2c[28], a1[512], a2[128];
    if (t < 70) sq[t] = seq[(size_t)b * 70 + t];
    __syncthreads();
    if (t < 210) {
        int r = t / 42, o = t % 42; float v = bi_[o];
        for (int dd = 0; dd < 14; ++dd) v += sq[r * 14 + dd] * Wi[o * 14 + dd];
        qkv[t] = v;
    }
    __syncthreads();
    if (t < 25) {
        int r = t / 5, c = t % 5; float v = 0.f;
        for (int dd = 0; dd < 14; ++dd) v += qkv[r * 42 + dd] * qkv[c * 42 + 14 + dd];
        sc[t] = v / sqrtf(14.0f);
    }
    __syncthreads();
    if (t < 5) {
        float mx = sc[t * 5];
        for (int c = 1; c < 5; ++c) mx = fmaxf(mx, sc[t * 5 + c]);
        float e[5]; float sm = 0.f;
        for (int c = 0; c < 5; ++c) { e[c] = expf(sc[t * 5 + c] - mx); sm += e[c]; }
        for (int c = 0; c < 5; ++c) sc[t * 5 + c] = e[c] / sm;
    }
    __syncthreads();
    if (t < 70) {
        int r = t / 14, dd = t % 14; float v = 0.f;
        for (int c = 0; c < 5; ++c) v += sc[r * 5 + c] * qkv[c * 42 + 28 + dd];
        tmp[t] = v;
    }
    __syncthreads();
    if (t < 70) {
        int r = t / 14, o = t % 14; float v = bo[o];
        for (int dd = 0; dd < 14; ++dd) v += tmp[r * 14 + dd] * Wo[o * 14 + dd];
        f1[t] = sq[t] + v;                 // residual
    }
    __syncthreads();
    if (t < 5) {                           // LN1: f1 -> sq
        float m = 0.f; for (int dd = 0; dd < 14; ++dd) m += f1[t * 14 + dd]; m /= 14.f;
        float v = 0.f; for (int dd = 0; dd < 14; ++dd) { float z = f1[t * 14 + dd] - m; v += z * z; } v /= 14.f;
        float inv = 1.f / sqrtf(v + 1e-5f);
        for (int dd = 0; dd < 14; ++dd) sq[t * 14 + dd] = (f1[t * 14 + dd] - m) * inv * g1[dd] + be1[dd];
    }
    __syncthreads();
    if (t < 140) {
        int r = t / 28, o = t % 28; float v = bf1[o];
        for (int dd = 0; dd < 14; ++dd) v += sq[r * 14 + dd] * W1[o * 14 + dd];
        f1[t] = relu_(v);
    }
    __syncthreads();
    if (t < 70) {
        int r = t / 14, o = t % 14; float v = bf2[o];
        for (int i = 0; i < 28; ++i) v += f1[r * 28 + i] * W2[o * 28 + i];
        tmp[t] = sq[t] + v;                // residual
    }
    __syncthreads();
    if (t < 5) {                           // LN2: tmp -> sq
        float m = 0.f; for (int dd = 0; dd < 14; ++dd) m += tmp[t * 14 + dd]; m /= 14.f;
        float v = 0.f; for (int dd = 0; dd < 14; ++dd) { float z = tmp[t * 14 + dd] - m; v += z * z; } v /= 14.f;
        float inv = 1.f / sqrtf(v + 1e-5f);
        for (int dd = 0; dd < 14; ++dd) sq[t * 14 + dd] = (tmp[t * 14 + dd] - m) * inv * g2[dd] + be2[dd];
    }
    __syncthreads();
    if (t < 28) {
        int c = t - 14;
        h2c[t] = (t < 14) ? sq[t]
                          : 0.25f * (sq[14 + c] + sq[28 + c] + sq[42 + c] + sq[56 + c]);
    }
    __syncthreads();
    {
        int o = t;
        float v = hb1[o];
        for (int i = 0; i < 28; ++i) v += h2c[i] * H1[o * 28 + i];
        a1[o] = relu_(v);
        o = t + 256;
        v = hb1[o];
        for (int i = 0; i < 28; ++i) v += h2c[i] * H1[o * 28 + i];
        a1[o] = relu_(v);
    }
    __syncthreads();
    if (t < 128) {
        float v = hb2[t];
        for (int i = 0; i < 512; ++i) v += a1[i] * H2[t * 512 + i];
        a2[t] = relu_(v);
    }
    __syncthreads();
    if (t < 6) {
        float v = hb3[t];
        for (int i = 0; i < 128; ++i) v += a2[i] * H3[t * 128 + i];
        out[b * 6 + t] = v;
    }
}

extern "C" void kernel_launch(void* const* d_in, const int* in_sizes, int n_in,
                              void* d_out, int out_size, void* d_ws, size_t ws_size,
                              hipStream_t stream) {
    const float* x   = (const float*)d_in[0];
    const float* c1w = (const float*)d_in[1];
    const float* c1b = (const float*)d_in[2];
    const float* c2w = (const float*)d_in[3];
    const float* c2b = (const float*)d_in[4];
    const float* c3w = (const float*)d_in[5];
    const float* c3b = (const float*)d_in[6];
    const float* vew = (const float*)d_in[7];
    const float* veb = (const float*)d_in[8];
    const float* t1w = (const float*)d_in[9];
    const float* t1b = (const float*)d_in[10];
    const float* t2w = (const float*)d_in[11];
    const float* t2b = (const float*)d_in[12];
    const float* aiw = (const float*)d_in[13];
    const float* aib = (const float*)d_in[14];
    const float* aow = (const float*)d_in[15];
    const float* aob = (const float*)d_in[16];
    const float* l1g = (const float*)d_in[17];
    const float* l1bb= (const float*)d_in[18];
    const float* l2g = (const float*)d_in[19];
    const float* l2bb= (const float*)d_in[20];
    const float* f1w = (const float*)d_in[21];
    const float* f1b = (const float*)d_in[22];
    const float* f2w = (const float*)d_in[23];
    const float* f2b = (const float*)d_in[24];
    const float* h1w = (const float*)d_in[25];
    const float* h1b = (const float*)d_in[26];
    const float* h2w = (const float*)d_in[27];
    const float* h2b = (const float*)d_in[28];
    const float* h3w = (const float*)d_in[29];
    const float* h3b = (const float*)d_in[30];
    const float* nodes = (const float*)d_in[31];
    const float* edges = (const float*)d_in[32];

    float* W = (float*)d_ws;
    float* tenc   = W;                 // 896
    float* ve     = W + 1024;          // 512
    float* seqb   = W + 2048;          // 4480
    float* dvec   = W + 8192;          // 16384
    int*   closest= (int*)(W + 24576); // 64
    int*   topk   = (int*)(W + 24832); // 256
    float* h1     = W + 32768;         // 984064
    float* h2     = W + 1016832;       // 460800
    float* h3     = W + 1477632;       // 460800
    float* minout = W + 1938432;       // 98304
    float* cost   = W + 2097152;       // 4194304 (ends at ~25.2 MB)

    // independent front-ends
    k_tenc<<<64, 64, 0, stream>>>(x, t1w, t1b, t2w, t2b, tenc);
    k_conv1<<<(BB * 16 * 31 * 31 + 255) / 256, 256, 0, stream>>>(x, c1w, c1b, h1);
    k_conv2<<<(BB * 32 * 15 * 15 + 255) / 256, 256, 0, stream>>>(h1, c2w, c2b, h2);
    k_conv3<<<(BB * 32 * 15 * 15 + 255) / 256, 256, 0, stream>>>(h2, c3w, c3b, h3);
    k_venc<<<BB * 8, 256, 0, stream>>>(h3, vew, veb, ve);
    k_cost<<<BB * SS, 256, 0, stream>>>(edges, cost, minout);
    k_closest<<<BB, 256, 0, stream>>>(ve, nodes, closest);
    k_bellman<<<BB, 256, 0, stream>>>(cost, closest, dvec);
    k_seq<<<BB, 256, 0, stream>>>(dvec, tenc, nodes, minout, seqb, topk);
    k_head<<<BB, 256, 0, stream>>>(seqb, aiw, aib, aow, aob, l1g, l1bb, l2g, l2bb,
                                   f1w, f1b, f2w, f2b, h1w, h1b, h2w, h2b, h3w, h3b,
                                   (float*)d_out);
}

// Round 2
// 253.554 us; speedup vs baseline: 1.7498x; 1.7498x over previous
//
#include <hip/hip_runtime.h>
#include <math.h>

#define BB 64

static __device__ __forceinline__ float relu_(float v){ return v > 0.f ? v : 0.f; }

// ---------- cost part: block handles bi = b*256+i; cost=min over 6, minout=min over j ----------
static __device__ void cost_body(const float* __restrict__ edges, float* __restrict__ cost,
                                 float* __restrict__ minout, int bi, float* red) {
    int j = threadIdx.x;
    const float* e = edges + ((size_t)bi * 256 + j) * 6;
    float m0 = e[0], m1 = e[1], m2 = e[2], m3 = e[3], m4 = e[4], m5 = e[5];
    cost[(size_t)bi * 256 + j] = fminf(fminf(fminf(m0, m1), fminf(m2, m3)), fminf(m4, m5));
    red[0*256+j]=m0; red[1*256+j]=m1; red[2*256+j]=m2;
    red[3*256+j]=m3; red[4*256+j]=m4; red[5*256+j]=m5;
    __syncthreads();
    for (int st = 128; st > 0; st >>= 1) {
        if (j < st) {
            #pragma unroll
            for (int q = 0; q < 6; ++q) red[q*256+j] = fminf(red[q*256+j], red[q*256+j+st]);
        }
        __syncthreads();
    }
    if (j < 6) minout[(size_t)bi * 6 + j] = red[j*256];
}

// ---------------- conv1 (3->16, VALID, k3) + avgpool2 + relu, box-sum trick ----------------
#define C1_BLOCKS 128
__global__ __launch_bounds__(256) void k_conv1(const float* __restrict__ x, const float* __restrict__ w,
        const float* __restrict__ bias, float* __restrict__ h1,
        const float* __restrict__ edges, float* __restrict__ cost, float* __restrict__ minout, int costBase) {
    __shared__ float sm[2210 + 6435 + 432 + 16]; // iBuf[34][65], T[3][33][65], sW, sB
    if ((int)blockIdx.x >= C1_BLOCKS) {
        int bi = costBase + (int)blockIdx.x - C1_BLOCKS;
        if (bi < BB * 256) cost_body(edges, cost, minout, bi, sm);
        return;
    }
    float* iBuf = sm; float* T = sm + 2210; float* sW = T + 6435; float* sB = sW + 432;
    int b = blockIdx.x >> 1, rg = blockIdx.x & 1;
    int t = threadIdx.x;
    int nyo = rg ? 15 : 16;
    int r0 = rg * 16, rowbase = rg * 32;
    int nrows = rg ? 32 : 34;
    for (int i = t; i < 432; i += 256) sW[i] = w[i];
    if (t < 16) sB[t] = bias[t];
    int na = 2 * nyo + 1;          // T rows: a in [0, 2*(nyo-1)+2]
    for (int ci = 0; ci < 3; ++ci) {
        __syncthreads();           // iBuf reuse barrier
        int tot = nrows * 64;
        for (int e = t; e < tot; e += 256) {
            int r = e >> 6, c = e & 63;
            iBuf[r * 65 + c] = x[(size_t)b * 12288 + ci * 4096 + (rowbase + r) * 64 + c] - 0.5f;
        }
        __syncthreads();
        int tot2 = na * 63;
        for (int e2 = t; e2 < tot2; e2 += 256) {
            int a = e2 / 63, c = e2 % 63;
            float* p = iBuf + a * 65 + c;
            T[ci * 2145 + a * 65 + c] = (p[0] + p[1]) + (p[65] + p[66]);
        }
    }
    __syncthreads();
    int npos = 31 * nyo;
    int p1 = t + 256;
    int yo0 = t / 31, xo0 = t % 31;          // p0 = t always < npos (465/496)
    bool v1 = p1 < npos;
    int yo1 = v1 ? p1 / 31 : 0, xo1 = v1 ? p1 % 31 : 0;
    float acc0[16], acc1[16];
    #pragma unroll
    for (int o = 0; o < 16; ++o) { acc0[o] = 0.f; acc1[o] = 0.f; }
    #pragma unroll 1
    for (int ci = 0; ci < 3; ++ci) {
        const float* T0 = T + ci * 2145 + yo0 * 130 + xo0 * 2;
        const float* T1 = T + ci * 2145 + yo1 * 130 + xo1 * 2;
        #pragma unroll
        for (int ky = 0; ky < 3; ++ky)
        #pragma unroll
        for (int kx = 0; kx < 3; ++kx) {
            float s0 = T0[ky * 65 + kx], s1 = T1[ky * 65 + kx];
            #pragma unroll
            for (int o = 0; o < 16; ++o) {
                float wv = sW[o * 27 + ci * 9 + ky * 3 + kx];
                acc0[o] += s0 * wv; acc1[o] += s1 * wv;
            }
        }
    }
    size_t ob = (size_t)b * 15376;
    #pragma unroll
    for (int o = 0; o < 16; ++o) {
        h1[ob + o * 961 + (r0 + yo0) * 31 + xo0] = relu_(0.25f * acc0[o] + sB[o]);
        if (v1) h1[ob + o * 961 + (r0 + yo1) * 31 + xo1] = relu_(0.25f * acc1[o] + sB[o]);
    }
}

// ---------------- conv2 (16->32, pad1, k3) + avgpool2 + relu, box-sum trick ----------------
#define C2_BLOCKS 256
__global__ __launch_bounds__(256) void k_conv2(const float* __restrict__ h1, const float* __restrict__ w,
        const float* __restrict__ bias, float* __restrict__ h2,
        const float* __restrict__ edges, float* __restrict__ cost, float* __restrict__ minout, int costBase) {
    __shared__ float sm[1024 + 16368 + 1152 + 8]; // iBuf[32][32], T[16][31][33], sW, sB
    if ((int)blockIdx.x >= C2_BLOCKS) {
        int bi = costBase + (int)blockIdx.x - C2_BLOCKS;
        if (bi < BB * 256) cost_body(edges, cost, minout, bi, sm);
        return;
    }
    float* iBuf = sm; float* T = sm + 1024; float* sW = T + 16368; float* sB = sW + 1152;
    int b = blockIdx.x >> 2, og = blockIdx.x & 3;   // 8 out-channels per block
    int t = threadIdx.x;
    for (int i = t; i < 1152; i += 256) sW[i] = w[og * 1152 + i];
    if (t < 8) sB[t] = bias[og * 8 + t];
    for (int ci = 0; ci < 16; ++ci) {
        __syncthreads();
        for (int e = t; e < 1024; e += 256) {       // padded I: iy,ix in [-1,30]
            int r = e >> 5, c = e & 31;
            int iy = r - 1, ix = c - 1;
            float v = 0.f;
            if (iy >= 0 && iy < 31 && ix >= 0 && ix < 31)
                v = h1[(size_t)b * 15376 + ci * 961 + iy * 31 + ix];
            iBuf[e] = v;
        }
        __syncthreads();
        for (int e = t; e < 961; e += 256) {        // T[a][c], a,c in [0,30]
            int a = e / 31, c = e % 31;
            float* p = iBuf + a * 32 + c;
            T[ci * 1023 + a * 33 + c] = (p[0] + p[1]) + (p[32] + p[33]);
        }
    }
    __syncthreads();
    if (t < 225) {
        int yo = t / 15, xo = t % 15;
        float acc[8];
        #pragma unroll
        for (int o = 0; o < 8; ++o) acc[o] = 0.f;
        #pragma unroll 1
        for (int ci = 0; ci < 16; ++ci) {
            const float* Tp = T + ci * 1023 + yo * 66 + xo * 2;
            #pragma unroll
            for (int ky = 0; ky < 3; ++ky)
            #pragma unroll
            for (int kx = 0; kx < 3; ++kx) {
                float s = Tp[ky * 33 + kx];
                #pragma unroll
                for (int o = 0; o < 8; ++o) acc[o] += s * sW[o * 144 + ci * 9 + ky * 3 + kx];
            }
        }
        size_t ob = (size_t)b * 7200 + (og * 8) * 225 + t;
        #pragma unroll
        for (int o = 0; o < 8; ++o) h2[ob + o * 225] = relu_(0.25f * acc[o] + sB[o]);
    }
}

// ---------------- conv3 (32->32, pad1, k3) + relu ----------------
#define C3_BLOCKS 256
__global__ __launch_bounds__(256) void k_conv3(const float* __restrict__ h2, const float* __restrict__ w,
        const float* __restrict__ bias, float* __restrict__ h3,
        const float* __restrict__ edges, float* __restrict__ cost, float* __restrict__ minout, int costBase) {
    __shared__ float sm[9248 + 2304 + 8];  // sIn[32][17][17], sW, sB
    if ((int)blockIdx.x >= C3_BLOCKS) {
        int bi = costBase + (int)blockIdx.x - C3_BLOCKS;
        if (bi < BB * 256) cost_body(edges, cost, minout, bi, sm);
        return;
    }
    float* sIn = sm; float* sW = sm + 9248; float* sB = sW + 2304;
    int b = blockIdx.x >> 2, og = blockIdx.x & 3;   // 8 out-channels per block
    int t = threadIdx.x;
    for (int i = t; i < 2304; i += 256) sW[i] = w[og * 2304 + i];
    if (t < 8) sB[t] = bias[og * 8 + t];
    for (int e = t; e < 9248; e += 256) {           // padded input [-1,15]^2
        int ci = e / 289, rem = e % 289;
        int r = rem / 17, c = rem % 17;
        int iy = r - 1, ix = c - 1;
        float v = 0.f;
        if (iy >= 0 && iy < 15 && ix >= 0 && ix < 15)
            v = h2[(size_t)b * 7200 + ci * 225 + iy * 15 + ix];
        sIn[e] = v;
    }
    __syncthreads();
    if (t < 225) {
        int yo = t / 15, xo = t % 15;
        float acc[8];
        #pragma unroll
        for (int o = 0; o < 8; ++o) acc[o] = 0.f;
        #pragma unroll 1
        for (int ci = 0; ci < 32; ++ci) {
            const float* Ip = sIn + ci * 289 + yo * 17 + xo;
            const float* Wp = sW + ci * 9;
            #pragma unroll
            for (int ky = 0; ky < 3; ++ky)
            #pragma unroll
            for (int kx = 0; kx < 3; ++kx) {
                float iv = Ip[ky * 17 + kx];
                #pragma unroll
                for (int o = 0; o < 8; ++o) acc[o] += iv * Wp[o * 288 + ky * 3 + kx];
            }
        }
        size_t ob = (size_t)b * 7200 + (og * 8) * 225 + t;
        #pragma unroll
        for (int o = 0; o < 8; ++o) h3[ob + o * 225] = relu_(acc[o] + sB[o]);
    }
}

// ---------------- vision encoder linear 7200 -> 8 ----------------
__global__ void k_venc(const float* __restrict__ h3, const float* __restrict__ w,
                       const float* __restrict__ bias, float* __restrict__ ve) {
    int b = blockIdx.x >> 3; int f = blockIdx.x & 7; int tid = threadIdx.x;
    const float* hb = h3 + (size_t)b * 7200;
    const float* wf = w + (size_t)f * 7200;
    float s = 0.f;
    for (int i = tid; i < 7200; i += 256) s += hb[i] * wf[i];
    __shared__ float r[256];
    r[tid] = s; __syncthreads();
    for (int st = 128; st > 0; st >>= 1) { if (tid < st) r[tid] += r[tid + st]; __syncthreads(); }
    if (tid == 0) ve[b * 8 + f] = r[0] + bias[f];
}

// ---------------- closest (argmin dist) + Bellman fixed-point scan ----------------
__global__ void k_bellman(const float* __restrict__ ve, const float* __restrict__ nodes,
                          const float* __restrict__ cost, float* __restrict__ dout) {
    int b = blockIdx.x; int t = threadIdx.x;
    __shared__ float val[256]; __shared__ int idx[256];
    __shared__ float d[256]; __shared__ int changed; __shared__ int ssrc;
    {
        const float* n = nodes + ((size_t)b * 256 + t) * 8;
        const float* v = ve + b * 8;
        float acc = 0.f;
        #pragma unroll
        for (int f = 0; f < 8; ++f) { float df = v[f] - n[f]; acc += df * df; }
        val[t] = acc; idx[t] = t; __syncthreads();
        for (int st = 128; st > 0; st >>= 1) {
            if (t < st) {
                float ov = val[t + st]; int oi = idx[t + st];
                if (ov < val[t] || (ov == val[t] && oi < idx[t])) { val[t] = ov; idx[t] = oi; }
            }
            __syncthreads();
        }
        if (t == 0) ssrc = idx[0];
        __syncthreads();
    }
    int src = ssrc;
    const float* cb = cost + (size_t)b * 65536;
    float dv = cb[src * 256 + t];
    if (t == src) dv = 0.f;
    d[t] = dv;
    __syncthreads();
    for (int it = 0; it < 255; ++it) {
        float m = 3.402823466e+38f;
        for (int j = 0; j < 256; j += 4) {
            float a0 = d[j]     + cb[(j    ) * 256 + t];
            float a1 = d[j + 1] + cb[(j + 1) * 256 + t];
            float a2 = d[j + 2] + cb[(j + 2) * 256 + t];
            float a3 = d[j + 3] + cb[(j + 3) * 256 + t];
            m = fminf(m, fminf(fminf(a0, a1), fminf(a2, a3)));
        }
        float nd = fminf(dv, m);
        int ch = nd < dv;
        dv = nd;
        __syncthreads();
        if (t == 0) changed = 0;
        __syncthreads();
        d[t] = dv;
        if (ch) changed = 1;
        __syncthreads();
        if (!changed) break;          // fixed point: further iterations are identity
    }
    dout[(size_t)b * 256 + t] = dv;
}

// ---------------- tenc + top-K(4) + build seq (B,5,14) ----------------
__global__ void k_seq(const float* __restrict__ x,
                      const float* __restrict__ w1, const float* __restrict__ b1,
                      const float* __restrict__ w2, const float* __restrict__ b2,
                      const float* __restrict__ dvec, const float* __restrict__ nodes,
                      const float* __restrict__ minout, float* __restrict__ seq) {
    int b = blockIdx.x, t = threadIdx.x;
    __shared__ float tc[3]; __shared__ float tt[64]; __shared__ float te[14];
    if (t < 3) tc[t] = x[(size_t)b * 12288 + t * 4096];
    __syncthreads();
    if (t < 64) {
        float v = b1[t] + tc[0] * w1[t * 3] + tc[1] * w1[t * 3 + 1] + tc[2] * w1[t * 3 + 2];
        tt[t] = relu_(v);
    }
    __syncthreads();
    if (t < 14) {
        float e = b2[t];
        for (int o = 0; o < 64; ++o) e += tt[o] * w2[t * 64 + o];
        te[t] = e;
    }
    float dv = dvec[(size_t)b * 256 + t];
    if (isinf(dv)) dv = 1e9f;
    float myv = dv;
    __shared__ float val[256]; __shared__ int idx[256]; __shared__ int sel[4];
    for (int k = 0; k < 4; ++k) {
        val[t] = myv; idx[t] = t; __syncthreads();
        for (int st = 128; st > 0; st >>= 1) {
            if (t < st) {
                float ov = val[t + st]; int oi = idx[t + st];
                if (ov < val[t] || (ov == val[t] && oi < idx[t])) { val[t] = ov; idx[t] = oi; }
            }
            __syncthreads();
        }
        if (t == 0) sel[k] = idx[0];
        __syncthreads();
        if (t == sel[k]) myv = 3.402823466e+38f;
    }
    if (t < 14) seq[(size_t)b * 70 + t] = te[t];
    if (t >= 64 && t < 64 + 56) {
        int u = t - 64; int k = u / 14; int c = u % 14; int id_ = sel[k];
        float v = (c < 8) ? nodes[((size_t)b * 256 + id_) * 8 + c]
                          : minout[((size_t)b * 256 + id_) * 6 + (c - 8)];
        seq[(size_t)b * 70 + (1 + k) * 14 + c] = v;
    }
}

// ---------------- transformer block + MLP heads, one block per batch ----------------
__global__ void k_head(const float* __restrict__ seq,
                       const float* __restrict__ Wi, const float* __restrict__ bi_,
                       const float* __restrict__ Wo, const float* __restrict__ bo,
                       const float* __restrict__ g1, const float* __restrict__ be1,
                       const float* __restrict__ g2, const float* __restrict__ be2,
                       const float* __restrict__ W1, const float* __restrict__ bf1,
                       const float* __restrict__ W2, const float* __restrict__ bf2,
                       const float* __restrict__ H1, const float* __restrict__ hb1,
                       const float* __restrict__ H2, const float* __restrict__ hb2,
                       const float* __restrict__ H3, const float* __restrict__ hb3,
                       float* __restrict__ out) {
    int b = blockIdx.x, t = threadIdx.x;
    __shared__ float sq[70], qkv[210], sc[25], tmp[70], f1[140], h2c[28];
    __shared__ __align__(16) float a1[512];
    __shared__ float part[256]; __shared__ float a2[128];
    if (t < 70) sq[t] = seq[(size_t)b * 70 + t];
    __syncthreads();
    if (t < 210) {
        int r = t / 42, o = t % 42; float v = bi_[o];
        for (int dd = 0; dd < 14; ++dd) v += sq[r * 14 + dd] * Wi[o * 14 + dd];
        qkv[t] = v;
    }
    __syncthreads();
    if (t < 25) {
        int r = t / 5, c = t % 5; float v = 0.f;
        for (int dd = 0; dd < 14; ++dd) v += qkv[r * 42 + dd] * qkv[c * 42 + 14 + dd];
        sc[t] = v / sqrtf(14.0f);
    }
    __syncthreads();
    if (t < 5) {
        float mx = sc[t * 5];
        for (int c = 1; c < 5; ++c) mx = fmaxf(mx, sc[t * 5 + c]);
        float e[5]; float sm = 0.f;
        for (int c = 0; c < 5; ++c) { e[c] = expf(sc[t * 5 + c] - mx); sm += e[c]; }
        for (int c = 0; c < 5; ++c) sc[t * 5 + c] = e[c] / sm;
    }
    __syncthreads();
    if (t < 70) {
        int r = t / 14, dd = t % 14; float v = 0.f;
        for (int c = 0; c < 5; ++c) v += sc[r * 5 + c] * qkv[c * 42 + 28 + dd];
        tmp[t] = v;
    }
    __syncthreads();
    if (t < 70) {
        int r = t / 14, o = t % 14; float v = bo[o];
        for (int dd = 0; dd < 14; ++dd) v += tmp[r * 14 + dd] * Wo[o * 14 + dd];
        f1[t] = sq[t] + v;
    }
    __syncthreads();
    if (t < 5) {                           // LN1
        float m = 0.f; for (int dd = 0; dd < 14; ++dd) m += f1[t * 14 + dd]; m /= 14.f;
        float v = 0.f; for (int dd = 0; dd < 14; ++dd) { float z = f1[t * 14 + dd] - m; v += z * z; } v /= 14.f;
        float inv = 1.f / sqrtf(v + 1e-5f);
        for (int dd = 0; dd < 14; ++dd) sq[t * 14 + dd] = (f1[t * 14 + dd] - m) * inv * g1[dd] + be1[dd];
    }
    __syncthreads();
    if (t < 140) {
        int r = t / 28, o = t % 28; float v = bf1[o];
        for (int dd = 0; dd < 14; ++dd) v += sq[r * 14 + dd] * W1[o * 14 + dd];
        f1[t] = relu_(v);
    }
    __syncthreads();
    if (t < 70) {
        int r = t / 14, o = t % 14; float v = bf2[o];
        for (int i = 0; i < 28; ++i) v += f1[r * 28 + i] * W2[o * 28 + i];
        tmp[t] = sq[t] + v;
    }
    __syncthreads();
    if (t < 5) {                           // LN2
        float m = 0.f; for (int dd = 0; dd < 14; ++dd) m += tmp[t * 14 + dd]; m /= 14.f;
        float v = 0.f; for (int dd = 0; dd < 14; ++dd) { float z = tmp[t * 14 + dd] - m; v += z * z; } v /= 14.f;
        float inv = 1.f / sqrtf(v + 1e-5f);
        for (int dd = 0; dd < 14; ++dd) sq[t * 14 + dd] = (tmp[t * 14 + dd] - m) * inv * g2[dd] + be2[dd];
    }
    __syncthreads();
    if (t < 28) {
        int c = t - 14;
        h2c[t] = (t < 14) ? sq[t]
                          : 0.25f * (sq[14 + c] + sq[28 + c] + sq[42 + c] + sq[56 + c]);
    }
    __syncthreads();
    {   // head1: 28 -> 512, two outputs per thread, float4 weight rows
        #pragma unroll
        for (int rep = 0; rep < 2; ++rep) {
            int o = t + rep * 256;
            const float4* Hr = (const float4*)(H1 + o * 28);
            float v = hb1[o];
            #pragma unroll
            for (int i = 0; i < 7; ++i) {
                float4 h4 = Hr[i];
                v += h4.x * h2c[i*4] + h4.y * h2c[i*4+1] + h4.z * h2c[i*4+2] + h4.w * h2c[i*4+3];
            }
            a1[o] = relu_(v);
        }
    }
    __syncthreads();
    {   // head2: 512 -> 128, split each dot over 2 threads
        int o = t & 127, half = t >> 7;
        const float4* Hr = (const float4*)(H2 + o * 512 + half * 256);
        const float* ap = a1 + half * 256;
        float v = 0.f;
        for (int i = 0; i < 64; ++i) {
            float4 h4 = Hr[i];
            v += h4.x * ap[i*4] + h4.y * ap[i*4+1] + h4.z * ap[i*4+2] + h4.w * ap[i*4+3];
        }
        part[t] = v;
    }
    __syncthreads();
    if (t < 128) a2[t] = relu_(hb2[t] + part[t] + part[t + 128]);
    __syncthreads();
    if (t < 6) {
        const float4* Hr = (const float4*)(H3 + t * 128);
        float v = hb3[t];
        for (int i = 0; i < 32; ++i) {
            float4 h4 = Hr[i];
            v += h4.x * a2[i*4] + h4.y * a2[i*4+1] + h4.z * a2[i*4+2] + h4.w * a2[i*4+3];
        }
        out[b * 6 + t] = v;
    }
}

extern "C" void kernel_launch(void* const* d_in, const int* in_sizes, int n_in,
                              void* d_out, int out_size, void* d_ws, size_t ws_size,
                              hipStream_t stream) {
    const float* x   = (const float*)d_in[0];
    const float* c1w = (const float*)d_in[1];
    const float* c1b = (const float*)d_in[2];
    const float* c2w = (const float*)d_in[3];
    const float* c2b = (const float*)d_in[4];
    const float* c3w = (const float*)d_in[5];
    const float* c3b = (const float*)d_in[6];
    const float* vew = (const float*)d_in[7];
    const float* veb = (const float*)d_in[8];
    const float* t1w = (const float*)d_in[9];
    const float* t1b = (const float*)d_in[10];
    const float* t2w = (const float*)d_in[11];
    const float* t2b = (const float*)d_in[12];
    const float* aiw = (const float*)d_in[13];
    const float* aib = (const float*)d_in[14];
    const float* aow = (const float*)d_in[15];
    const float* aob = (const float*)d_in[16];
    const float* l1g = (const float*)d_in[17];
    const float* l1bb= (const float*)d_in[18];
    const float* l2g = (const float*)d_in[19];
    const float* l2bb= (const float*)d_in[20];
    const float* f1w = (const float*)d_in[21];
    const float* f1b = (const float*)d_in[22];
    const float* f2w = (const float*)d_in[23];
    const float* f2b = (const float*)d_in[24];
    const float* h1w = (const float*)d_in[25];
    const float* h1b = (const float*)d_in[26];
    const float* h2w = (const float*)d_in[27];
    const float* h2b = (const float*)d_in[28];
    const float* h3w = (const float*)d_in[29];
    const float* h3b = (const float*)d_in[30];
    const float* nodes = (const float*)d_in[31];
    const float* edges = (const float*)d_in[32];

    float* W = (float*)d_ws;
    float* ve     = W + 1024;          // 512
    float* seqb   = W + 2048;          // 4480
    float* dvec   = W + 8192;          // 16384
    float* h1     = W + 32768;         // 984064
    float* h2     = W + 1016832;       // 460800
    float* h3     = W + 1477632;       // 460800
    float* minout = W + 1938432;       // 98304
    float* cost   = W + 2097152;       // 4194304

    // cost pass (16384 blocks) split across the three conv kernels as grid appendices
    const int nc1 = 5461, nc2 = 5461, nc3 = 5462;
    k_conv1<<<C1_BLOCKS + nc1, 256, 0, stream>>>(x, c1w, c1b, h1, edges, cost, minout, 0);
    k_conv2<<<C2_BLOCKS + nc2, 256, 0, stream>>>(h1, c2w, c2b, h2, edges, cost, minout, nc1);
    k_conv3<<<C3_BLOCKS + nc3, 256, 0, stream>>>(h2, c3w, c3b, h3, edges, cost, minout, nc1 + nc2);
    k_venc<<<BB * 8, 256, 0, stream>>>(h3, vew, veb, ve);
    k_bellman<<<BB, 256, 0, stream>>>(ve, nodes, cost, dvec);
    k_seq<<<BB, 256, 0, stream>>>(x, t1w, t1b, t2w, t2b, dvec, nodes, minout, seqb);
    k_head<<<BB, 256, 0, stream>>>(seqb, aiw, aib, aow, aob, l1g, l1bb, l2g, l2bb,
                                   f1w, f1b, f2w, f2b, h1w, h1b, h2w, h2b, h3w, h3b,
                                   (float*)d_out);
}

// Round 3
// 169.904 us; speedup vs baseline: 2.6113x; 1.4923x over previous
//
#include <hip/hip_runtime.h>
#include <math.h>

#define BB 64

static __device__ __forceinline__ float relu_(float v){ return v > 0.f ? v : 0.f; }

// ---------- cost part: block handles bi = b*256+i; cost=min over 6, minout=min over j ----------
static __device__ void cost_body(const float* __restrict__ edges, float* __restrict__ cost,
                                 float* __restrict__ minout, int bi, float* red) {
    int j = threadIdx.x;
    const float* e = edges + ((size_t)bi * 256 + j) * 6;
    float m0 = e[0], m1 = e[1], m2 = e[2], m3 = e[3], m4 = e[4], m5 = e[5];
    cost[(size_t)bi * 256 + j] = fminf(fminf(fminf(m0, m1), fminf(m2, m3)), fminf(m4, m5));
    red[0*256+j]=m0; red[1*256+j]=m1; red[2*256+j]=m2;
    red[3*256+j]=m3; red[4*256+j]=m4; red[5*256+j]=m5;
    __syncthreads();
    for (int st = 128; st > 0; st >>= 1) {
        if (j < st) {
            #pragma unroll
            for (int q = 0; q < 6; ++q) red[q*256+j] = fminf(red[q*256+j], red[q*256+j+st]);
        }
        __syncthreads();
    }
    if (j < 6) minout[(size_t)bi * 6 + j] = red[j*256];
}

// ---------------- conv1 (3->16, VALID, k3) + avgpool2 + relu, box-sum trick ----------------
#define C1_BLOCKS 128
__global__ __launch_bounds__(256) void k_conv1(const float* __restrict__ x, const float* __restrict__ w,
        const float* __restrict__ bias, float* __restrict__ h1,
        const float* __restrict__ edges, float* __restrict__ cost, float* __restrict__ minout, int costBase) {
    __shared__ float sm[2210 + 6435 + 432 + 16]; // iBuf[34][65], T[3][33][65], sW, sB
    if ((int)blockIdx.x >= C1_BLOCKS) {
        int bi = costBase + (int)blockIdx.x - C1_BLOCKS;
        if (bi < BB * 256) cost_body(edges, cost, minout, bi, sm);
        return;
    }
    float* iBuf = sm; float* T = sm + 2210; float* sW = T + 6435; float* sB = sW + 432;
    int b = blockIdx.x >> 1, rg = blockIdx.x & 1;
    int t = threadIdx.x;
    int nyo = rg ? 15 : 16;
    int r0 = rg * 16, rowbase = rg * 32;
    int nrows = rg ? 32 : 34;
    for (int i = t; i < 432; i += 256) sW[i] = w[i];
    if (t < 16) sB[t] = bias[t];
    int na = 2 * nyo + 1;
    for (int ci = 0; ci < 3; ++ci) {
        __syncthreads();
        int tot = nrows * 64;
        for (int e = t; e < tot; e += 256) {
            int r = e >> 6, c = e & 63;
            iBuf[r * 65 + c] = x[(size_t)b * 12288 + ci * 4096 + (rowbase + r) * 64 + c] - 0.5f;
        }
        __syncthreads();
        int tot2 = na * 63;
        for (int e2 = t; e2 < tot2; e2 += 256) {
            int a = e2 / 63, c = e2 % 63;
            float* p = iBuf + a * 65 + c;
            T[ci * 2145 + a * 65 + c] = (p[0] + p[1]) + (p[65] + p[66]);
        }
    }
    __syncthreads();
    int npos = 31 * nyo;
    int p1 = t + 256;
    int yo0 = t / 31, xo0 = t % 31;
    bool v1 = p1 < npos;
    int yo1 = v1 ? p1 / 31 : 0, xo1 = v1 ? p1 % 31 : 0;
    float acc0[16], acc1[16];
    #pragma unroll
    for (int o = 0; o < 16; ++o) { acc0[o] = 0.f; acc1[o] = 0.f; }
    #pragma unroll 1
    for (int ci = 0; ci < 3; ++ci) {
        const float* T0 = T + ci * 2145 + yo0 * 130 + xo0 * 2;
        const float* T1 = T + ci * 2145 + yo1 * 130 + xo1 * 2;
        #pragma unroll
        for (int ky = 0; ky < 3; ++ky)
        #pragma unroll
        for (int kx = 0; kx < 3; ++kx) {
            float s0 = T0[ky * 65 + kx], s1 = T1[ky * 65 + kx];
            #pragma unroll
            for (int o = 0; o < 16; ++o) {
                float wv = sW[o * 27 + ci * 9 + ky * 3 + kx];
                acc0[o] += s0 * wv; acc1[o] += s1 * wv;
            }
        }
    }
    size_t ob = (size_t)b * 15376;
    #pragma unroll
    for (int o = 0; o < 16; ++o) {
        h1[ob + o * 961 + (r0 + yo0) * 31 + xo0] = relu_(0.25f * acc0[o] + sB[o]);
        if (v1) h1[ob + o * 961 + (r0 + yo1) * 31 + xo1] = relu_(0.25f * acc1[o] + sB[o]);
    }
}

// ---------------- conv2 (16->32, pad1, k3) + avgpool2 + relu, box-sum trick ----------------
#define C2_BLOCKS 256
__global__ __launch_bounds__(256) void k_conv2(const float* __restrict__ h1, const float* __restrict__ w,
        const float* __restrict__ bias, float* __restrict__ h2,
        const float* __restrict__ edges, float* __restrict__ cost, float* __restrict__ minout, int costBase) {
    __shared__ float sm[1024 + 16368 + 1152 + 8]; // iBuf[32][32], T[16][31][33], sW, sB
    if ((int)blockIdx.x >= C2_BLOCKS) {
        int bi = costBase + (int)blockIdx.x - C2_BLOCKS;
        if (bi < BB * 256) cost_body(edges, cost, minout, bi, sm);
        return;
    }
    float* iBuf = sm; float* T = sm + 1024; float* sW = T + 16368; float* sB = sW + 1152;
    int b = blockIdx.x >> 2, og = blockIdx.x & 3;
    int t = threadIdx.x;
    for (int i = t; i < 1152; i += 256) sW[i] = w[og * 1152 + i];
    if (t < 8) sB[t] = bias[og * 8 + t];
    for (int ci = 0; ci < 16; ++ci) {
        __syncthreads();
        for (int e = t; e < 1024; e += 256) {
            int r = e >> 5, c = e & 31;
            int iy = r - 1, ix = c - 1;
            float v = 0.f;
            if (iy >= 0 && iy < 31 && ix >= 0 && ix < 31)
                v = h1[(size_t)b * 15376 + ci * 961 + iy * 31 + ix];
            iBuf[e] = v;
        }
        __syncthreads();
        for (int e = t; e < 961; e += 256) {
            int a = e / 31, c = e % 31;
            float* p = iBuf + a * 32 + c;
            T[ci * 1023 + a * 33 + c] = (p[0] + p[1]) + (p[32] + p[33]);
        }
    }
    __syncthreads();
    if (t < 225) {
        int yo = t / 15, xo = t % 15;
        float acc[8];
        #pragma unroll
        for (int o = 0; o < 8; ++o) acc[o] = 0.f;
        #pragma unroll 1
        for (int ci = 0; ci < 16; ++ci) {
            const float* Tp = T + ci * 1023 + yo * 66 + xo * 2;
            #pragma unroll
            for (int ky = 0; ky < 3; ++ky)
            #pragma unroll
            for (int kx = 0; kx < 3; ++kx) {
                float s = Tp[ky * 33 + kx];
                #pragma unroll
                for (int o = 0; o < 8; ++o) acc[o] += s * sW[o * 144 + ci * 9 + ky * 3 + kx];
            }
        }
        size_t ob = (size_t)b * 7200 + (og * 8) * 225 + t;
        #pragma unroll
        for (int o = 0; o < 8; ++o) h2[ob + o * 225] = relu_(0.25f * acc[o] + sB[o]);
    }
}

// ---------------- conv3 (32->32, pad1, k3) + relu ----------------
#define C3_BLOCKS 256
__global__ __launch_bounds__(256) void k_conv3(const float* __restrict__ h2, const float* __restrict__ w,
        const float* __restrict__ bias, float* __restrict__ h3,
        const float* __restrict__ edges, float* __restrict__ cost, float* __restrict__ minout, int costBase) {
    __shared__ float sm[9248 + 2304 + 8];  // sIn[32][17][17], sW, sB
    if ((int)blockIdx.x >= C3_BLOCKS) {
        int bi = costBase + (int)blockIdx.x - C3_BLOCKS;
        if (bi < BB * 256) cost_body(edges, cost, minout, bi, sm);
        return;
    }
    float* sIn = sm; float* sW = sm + 9248; float* sB = sW + 2304;
    int b = blockIdx.x >> 2, og = blockIdx.x & 3;
    int t = threadIdx.x;
    for (int i = t; i < 2304; i += 256) sW[i] = w[og * 2304 + i];
    if (t < 8) sB[t] = bias[og * 8 + t];
    for (int e = t; e < 9248; e += 256) {
        int ci = e / 289, rem = e % 289;
        int r = rem / 17, c = rem % 17;
        int iy = r - 1, ix = c - 1;
        float v = 0.f;
        if (iy >= 0 && iy < 15 && ix >= 0 && ix < 15)
            v = h2[(size_t)b * 7200 + ci * 225 + iy * 15 + ix];
        sIn[e] = v;
    }
    __syncthreads();
    if (t < 225) {
        int yo = t / 15, xo = t % 15;
        float acc[8];
        #pragma unroll
        for (int o = 0; o < 8; ++o) acc[o] = 0.f;
        #pragma unroll 1
        for (int ci = 0; ci < 32; ++ci) {
            const float* Ip = sIn + ci * 289 + yo * 17 + xo;
            const float* Wp = sW + ci * 9;
            #pragma unroll
            for (int ky = 0; ky < 3; ++ky)
            #pragma unroll
            for (int kx = 0; kx < 3; ++kx) {
                float iv = Ip[ky * 17 + kx];
                #pragma unroll
                for (int o = 0; o < 8; ++o) acc[o] += iv * Wp[o * 288 + ky * 3 + kx];
            }
        }
        size_t ob = (size_t)b * 7200 + (og * 8) * 225 + t;
        #pragma unroll
        for (int o = 0; o < 8; ++o) h3[ob + o * 225] = relu_(acc[o] + sB[o]);
    }
}

// ------- venc (7200->8) + closest argmin + Bellman fixed-point, cost columns in registers -------
// 1024 threads: thread (jg = tid>>8, t = tid&255) owns cost[jg*64+jj][t] in 64 VGPRs.
__global__ __launch_bounds__(1024, 4) void k_bellman(
        const float* __restrict__ h3, const float* __restrict__ vew, const float* __restrict__ veb,
        const float* __restrict__ nodes, const float* __restrict__ cost, float* __restrict__ dout) {
    int b = blockIdx.x; int tid = threadIdx.x;
    __shared__ float vred[1024];
    __shared__ float ve_s[8];
    __shared__ float val[256]; __shared__ int idx[256];
    __shared__ __align__(16) float d_lds[256];
    __shared__ __align__(16) float part[1024];

    // phase 0: vision encoder ve[8] = h3[b] @ venc_w.T + b
    {
        int f = tid >> 7, i = tid & 127;
        const float* hb = h3 + (size_t)b * 7200;
        const float* wf = vew + (size_t)f * 7200;
        float s = 0.f;
        for (int k = i; k < 7200; k += 128) s += hb[k] * wf[k];
        vred[tid] = s; __syncthreads();
        for (int st = 64; st > 0; st >>= 1) {
            if (i < st) vred[tid] += vred[tid + st];
            __syncthreads();
        }
        if (i == 0) ve_s[f] = vred[tid] + veb[f];
        __syncthreads();
    }
    // phase 1: closest = argmin_s ||ve - nodes[b,s]|| (tie -> lowest index)
    if (tid < 256) {
        const float* n = nodes + ((size_t)b * 256 + tid) * 8;
        float acc = 0.f;
        #pragma unroll
        for (int f = 0; f < 8; ++f) { float df = ve_s[f] - n[f]; acc += df * df; }
        val[tid] = acc; idx[tid] = tid;
    }
    __syncthreads();
    for (int st = 128; st > 0; st >>= 1) {
        if (tid < st) {
            float ov = val[tid + st]; int oi = idx[tid + st];
            if (ov < val[tid] || (ov == val[tid] && oi < idx[tid])) { val[tid] = ov; idx[tid] = oi; }
        }
        __syncthreads();
    }
    int src = idx[0];
    // phase 2: stage cost columns into registers; init d
    int jg = tid >> 8, t = tid & 255;
    const float* cb = cost + (size_t)b * 65536;
    float creg[64];
    #pragma unroll
    for (int jj = 0; jj < 64; ++jj)
        creg[jj] = cb[(size_t)((jg << 6) | jj) * 256 + t];
    float dv = 0.f;
    if (jg == 0) {
        dv = (t == src) ? 0.f : cb[(size_t)src * 256 + t];
        d_lds[t] = dv;
    }
    __syncthreads();
    // phase 3: Jacobi relaxation to fixed point (early exit == bitwise identical)
    for (int it = 0; it < 255; ++it) {
        float p = 3.402823466e+38f;
        const float4* d4 = (const float4*)(d_lds + (jg << 6));
        #pragma unroll
        for (int q = 0; q < 16; ++q) {
            float4 dd = d4[q];
            p = fminf(p, fminf(fminf(dd.x + creg[4*q+0], dd.y + creg[4*q+1]),
                               fminf(dd.z + creg[4*q+2], dd.w + creg[4*q+3])));
        }
        part[(jg << 8) | t] = p;
        __syncthreads();
        int ch = 0;
        if (jg == 0) {
            float m = fminf(fminf(part[t], part[256 + t]), fminf(part[512 + t], part[768 + t]));
            float nd = fminf(dv, m);
            ch = nd < dv;
            dv = nd;
            d_lds[t] = nd;
        }
        if (__syncthreads_count(ch) == 0) break;   // barrier + all-reduce; d_lds visible next iter
    }
    if (jg == 0) dout[(size_t)b * 256 + t] = dv;
}

// ------- tenc + top-K(4) + seq build + transformer block + MLP heads, one block per batch -------
__global__ void k_head(const float* __restrict__ x,
                       const float* __restrict__ w1, const float* __restrict__ b1,
                       const float* __restrict__ w2, const float* __restrict__ b2,
                       const float* __restrict__ dvec, const float* __restrict__ nodes,
                       const float* __restrict__ minout,
                       const float* __restrict__ Wi, const float* __restrict__ bi_,
                       const float* __restrict__ Wo, const float* __restrict__ bo,
                       const float* __restrict__ g1, const float* __restrict__ be1,
                       const float* __restrict__ g2, const float* __restrict__ be2,
                       const float* __restrict__ W1, const float* __restrict__ bf1,
                       const float* __restrict__ W2, const float* __restrict__ bf2,
                       const float* __restrict__ H1, const float* __restrict__ hb1,
                       const float* __restrict__ H2, const float* __restrict__ hb2,
                       const float* __restrict__ H3, const float* __restrict__ hb3,
                       float* __restrict__ out) {
    int b = blockIdx.x, t = threadIdx.x;
    __shared__ float sq[70], qkv[210], sc[25], tmp[70], f1[140], h2c[28];
    __shared__ __align__(16) float a1[512];
    __shared__ float part[256]; __shared__ float a2[128];
    __shared__ float tc[3]; __shared__ float tt[64];
    __shared__ float val[256]; __shared__ int idx[256]; __shared__ int sel[4];

    // seq phase: target encoder -> sq[0..13]
    if (t < 3) tc[t] = x[(size_t)b * 12288 + t * 4096];
    __syncthreads();
    if (t < 64) tt[t] = relu_(b1[t] + tc[0] * w1[t * 3] + tc[1] * w1[t * 3 + 1] + tc[2] * w1[t * 3 + 2]);
    __syncthreads();
    if (t < 14) {
        float e = b2[t];
        for (int o = 0; o < 64; ++o) e += tt[o] * w2[t * 64 + o];
        sq[t] = e;
    }
    // top-K(4) smallest spd (tie -> lowest index)
    float dv = dvec[(size_t)b * 256 + t];
    if (isinf(dv)) dv = 1e9f;
    float myv = dv;
    for (int k = 0; k < 4; ++k) {
        val[t] = myv; idx[t] = t; __syncthreads();
        for (int st = 128; st > 0; st >>= 1) {
            if (t < st) {
                float ov = val[t + st]; int oi = idx[t + st];
                if (ov < val[t] || (ov == val[t] && oi < idx[t])) { val[t] = ov; idx[t] = oi; }
            }
            __syncthreads();
        }
        if (t == 0) sel[k] = idx[0];
        __syncthreads();
        if (t == sel[k]) myv = 3.402823466e+38f;
    }
    if (t >= 64 && t < 64 + 56) {
        int u = t - 64; int k = u / 14; int c = u % 14; int id_ = sel[k];
        sq[(1 + k) * 14 + c] = (c < 8) ? nodes[((size_t)b * 256 + id_) * 8 + c]
                                       : minout[((size_t)b * 256 + id_) * 6 + (c - 8)];
    }
    __syncthreads();

    // transformer block
    if (t < 210) {
        int r = t / 42, o = t % 42; float v = bi_[o];
        for (int dd = 0; dd < 14; ++dd) v += sq[r * 14 + dd] * Wi[o * 14 + dd];
        qkv[t] = v;
    }
    __syncthreads();
    if (t < 25) {
        int r = t / 5, c = t % 5; float v = 0.f;
        for (int dd = 0; dd < 14; ++dd) v += qkv[r * 42 + dd] * qkv[c * 42 + 14 + dd];
        sc[t] = v / sqrtf(14.0f);
    }
    __syncthreads();
    if (t < 5) {
        float mx = sc[t * 5];
        for (int c = 1; c < 5; ++c) mx = fmaxf(mx, sc[t * 5 + c]);
        float e[5]; float sm = 0.f;
        for (int c = 0; c < 5; ++c) { e[c] = expf(sc[t * 5 + c] - mx); sm += e[c]; }
        for (int c = 0; c < 5; ++c) sc[t * 5 + c] = e[c] / sm;
    }
    __syncthreads();
    if (t < 70) {
        int r = t / 14, dd = t % 14; float v = 0.f;
        for (int c = 0; c < 5; ++c) v += sc[r * 5 + c] * qkv[c * 42 + 28 + dd];
        tmp[t] = v;
    }
    __syncthreads();
    if (t < 70) {
        int r = t / 14, o = t % 14; float v = bo[o];
        for (int dd = 0; dd < 14; ++dd) v += tmp[r * 14 + dd] * Wo[o * 14 + dd];
        f1[t] = sq[t] + v;
    }
    __syncthreads();
    if (t < 5) {                           // LN1
        float m = 0.f; for (int dd = 0; dd < 14; ++dd) m += f1[t * 14 + dd]; m /= 14.f;
        float v = 0.f; for (int dd = 0; dd < 14; ++dd) { float z = f1[t * 14 + dd] - m; v += z * z; } v /= 14.f;
        float inv = 1.f / sqrtf(v + 1e-5f);
        for (int dd = 0; dd < 14; ++dd) sq[t * 14 + dd] = (f1[t * 14 + dd] - m) * inv * g1[dd] + be1[dd];
    }
    __syncthreads();
    if (t < 140) {
        int r = t / 28, o = t % 28; float v = bf1[o];
        for (int dd = 0; dd < 14; ++dd) v += sq[r * 14 + dd] * W1[o * 14 + dd];
        f1[t] = relu_(v);
    }
    __syncthreads();
    if (t < 70) {
        int r = t / 14, o = t % 14; float v = bf2[o];
        for (int i = 0; i < 28; ++i) v += f1[r * 28 + i] * W2[o * 28 + i];
        tmp[t] = sq[t] + v;
    }
    __syncthreads();
    if (t < 5) {                           // LN2
        float m = 0.f; for (int dd = 0; dd < 14; ++dd) m += tmp[t * 14 + dd]; m /= 14.f;
        float v = 0.f; for (int dd = 0; dd < 14; ++dd) { float z = tmp[t * 14 + dd] - m; v += z * z; } v /= 14.f;
        float inv = 1.f / sqrtf(v + 1e-5f);
        for (int dd = 0; dd < 14; ++dd) sq[t * 14 + dd] = (tmp[t * 14 + dd] - m) * inv * g2[dd] + be2[dd];
    }
    __syncthreads();
    if (t < 28) {
        int c = t - 14;
        h2c[t] = (t < 14) ? sq[t]
                          : 0.25f * (sq[14 + c] + sq[28 + c] + sq[42 + c] + sq[56 + c]);
    }
    __syncthreads();
    {   // head1: 28 -> 512
        #pragma unroll
        for (int rep = 0; rep < 2; ++rep) {
            int o = t + rep * 256;
            const float4* Hr = (const float4*)(H1 + o * 28);
            float v = hb1[o];
            #pragma unroll
            for (int i = 0; i < 7; ++i) {
                float4 h4 = Hr[i];
                v += h4.x * h2c[i*4] + h4.y * h2c[i*4+1] + h4.z * h2c[i*4+2] + h4.w * h2c[i*4+3];
            }
            a1[o] = relu_(v);
        }
    }
    __syncthreads();
    {   // head2: 512 -> 128, dot split over 2 threads
        int o = t & 127, half = t >> 7;
        const float4* Hr = (const float4*)(H2 + o * 512 + half * 256);
        const float* ap = a1 + half * 256;
        float v = 0.f;
        for (int i = 0; i < 64; ++i) {
            float4 h4 = Hr[i];
            v += h4.x * ap[i*4] + h4.y * ap[i*4+1] + h4.z * ap[i*4+2] + h4.w * ap[i*4+3];
        }
        part[t] = v;
    }
    __syncthreads();
    if (t < 128) a2[t] = relu_(hb2[t] + part[t] + part[t + 128]);
    __syncthreads();
    if (t < 6) {
        const float4* Hr = (const float4*)(H3 + t * 128);
        float v = hb3[t];
        for (int i = 0; i < 32; ++i) {
            float4 h4 = Hr[i];
            v += h4.x * a2[i*4] + h4.y * a2[i*4+1] + h4.z * a2[i*4+2] + h4.w * a2[i*4+3];
        }
        out[b * 6 + t] = v;
    }
}

extern "C" void kernel_launch(void* const* d_in, const int* in_sizes, int n_in,
                              void* d_out, int out_size, void* d_ws, size_t ws_size,
                              hipStream_t stream) {
    const float* x   = (const float*)d_in[0];
    const float* c1w = (const float*)d_in[1];
    const float* c1b = (const float*)d_in[2];
    const float* c2w = (const float*)d_in[3];
    const float* c2b = (const float*)d_in[4];
    const float* c3w = (const float*)d_in[5];
    const float* c3b = (const float*)d_in[6];
    const float* vew = (const float*)d_in[7];
    const float* veb = (const float*)d_in[8];
    const float* t1w = (const float*)d_in[9];
    const float* t1b = (const float*)d_in[10];
    const float* t2w = (const float*)d_in[11];
    const float* t2b = (const float*)d_in[12];
    const float* aiw = (const float*)d_in[13];
    const float* aib = (const float*)d_in[14];
    const float* aow = (const float*)d_in[15];
    const float* aob = (const float*)d_in[16];
    const float* l1g = (const float*)d_in[17];
    const float* l1bb= (const float*)d_in[18];
    const float* l2g = (const float*)d_in[19];
    const float* l2bb= (const float*)d_in[20];
    const float* f1w = (const float*)d_in[21];
    const float* f1b = (const float*)d_in[22];
    const float* f2w = (const float*)d_in[23];
    const float* f2b = (const float*)d_in[24];
    const float* h1w = (const float*)d_in[25];
    const float* h1b = (const float*)d_in[26];
    const float* h2w = (const float*)d_in[27];
    const float* h2b = (const float*)d_in[28];
    const float* h3w = (const float*)d_in[29];
    const float* h3b = (const float*)d_in[30];
    const float* nodes = (const float*)d_in[31];
    const float* edges = (const float*)d_in[32];

    float* W = (float*)d_ws;
    float* dvec   = W + 8192;          // 16384
    float* h1     = W + 32768;         // 984064
    float* h2     = W + 1016832;       // 460800
    float* h3     = W + 1477632;       // 460800
    float* minout = W + 1938432;       // 98304
    float* cost   = W + 2097152;       // 4194304

    // cost pass (16384 blocks) split across the three conv kernels as grid appendices
    const int nc1 = 5461, nc2 = 5461, nc3 = 5462;
    k_conv1<<<C1_BLOCKS + nc1, 256, 0, stream>>>(x, c1w, c1b, h1, edges, cost, minout, 0);
    k_conv2<<<C2_BLOCKS + nc2, 256, 0, stream>>>(h1, c2w, c2b, h2, edges, cost, minout, nc1);
    k_conv3<<<C3_BLOCKS + nc3, 256, 0, stream>>>(h2, c3w, c3b, h3, edges, cost, minout, nc1 + nc2);
    k_bellman<<<BB, 1024, 0, stream>>>(h3, vew, veb, nodes, cost, dvec);
    k_head<<<BB, 256, 0, stream>>>(x, t1w, t1b, t2w, t2b, dvec, nodes, minout,
                                   aiw, aib, aow, aob, l1g, l1bb, l2g, l2bb,
                                   f1w, f1b, f2w, f2b, h1w, h1b, h2w, h2b, h3w, h3b,
                                   (float*)d_out);
}